// Round 12
// baseline (1569.534 us; speedup 1.0000x reference)
//
#include <hip/hip_runtime.h>
#include <hip/hip_bf16.h>
#include <cstdint>
#include <cstddef>

typedef _Float16 f16;
typedef _Float16 f16x8 __attribute__((ext_vector_type(8)));
typedef _Float16 f16x4 __attribute__((ext_vector_type(4)));
typedef float f32x4 __attribute__((ext_vector_type(4)));
typedef unsigned long long u64;
typedef unsigned int u32;

#define B_   256
#define T_   512
#define V_   50000
#define D_   256
#define H_   256
#define A_   128
#define N4H  1024

__device__ __forceinline__ float sigmoid_f(float x) {
    return __builtin_amdgcn_rcpf(1.f + __expf(-x));
}
__device__ __forceinline__ float tanh_f(float x) {
    float e = __expf(-2.f * fabsf(x));
    float t = 1.f - 2.f * e * __builtin_amdgcn_rcpf(1.f + e);
    return copysignf(t, x);
}

// asm MFMA with B operand taken straight from AGPRs (no accvgpr_read moves)
#define MFMA_A(accv, afragv, bfraga)                                         \
    asm volatile("v_mfma_f32_16x16x32_f16 %0, %1, %2, %0"                    \
                 : "+v"(accv) : "v"(afragv), "a"(bfraga))

// LDS-drain-only barrier: keeps global loads/stores (polls!) in flight
// across the barrier; only LDS ordering is enforced. Verified round 4.
#define LGKM_BARRIER()                                                       \
    do {                                                                     \
        asm volatile("s_waitcnt lgkmcnt(0)" ::: "memory");                   \
        __builtin_amdgcn_sched_barrier(0);                                   \
        __builtin_amdgcn_s_barrier();                                        \
        __builtin_amdgcn_sched_barrier(0);                                   \
    } while (0)

// ---------------------------------------------------------------------------
// K0: weight transpose + fp32->fp16 cast, fused with seqlen (blocks >= 1152).
// ---------------------------------------------------------------------------
__global__ __launch_bounds__(256) void k0_convert(
    const float* __restrict__ lstm_kernel, const float* __restrict__ w_omega,
    f16* __restrict__ WxT, f16* __restrict__ WhT, f16* __restrict__ WomT,
    const int* __restrict__ x, int* __restrict__ seqlen) {
    __shared__ int red[256];
    int blk = blockIdx.x;
    int tau = threadIdx.x;  // 0..255 (= k / h index)
    if (blk < N4H) {
        int n = blk;
        WxT[n * 256 + tau] = (f16)lstm_kernel[(size_t)tau * N4H + n];
        WhT[n * 256 + tau] = (f16)lstm_kernel[(size_t)(256 + tau) * N4H + n];
    } else if (blk < N4H + A_) {
        int a = blk - N4H;  // 0..127
        WomT[a * 256 + tau] = (f16)w_omega[(size_t)tau * A_ + a];
    } else {
        // seqlen for batch row b
        int b = blk - (N4H + A_);
        int cnt = (x[b * T_ + tau] != 0) + (x[b * T_ + tau + 256] != 0);
        red[tau] = cnt;
        __syncthreads();
        for (int s = 128; s > 0; s >>= 1) {
            if (tau < s) red[tau] += red[tau + s];
            __syncthreads();
        }
        if (tau == 0) seqlen[b] = red[0];
    }
}

// ===========================================================================
// Shared LDS arena size (union across LSTM / Zx producer / vu producer).
// ===========================================================================
#define SMEM_BYTES 87040

// ---------------------------------------------------------------------------
// Zx producer, 512-thread (128 rows/block), for chunk starting at t0.
// Zx column layout is half-split AND gate-interleaved:
// n = g*256 + half*128 + colu -> n'' = half*512 + colu*4 + g
// so the LSTM reads {i,j,f,o} for one unit as ONE ds_read_b64.
// ---------------------------------------------------------------------------
__device__ __forceinline__ void zx_producer(
    const int* __restrict__ x, const float* __restrict__ embed,
    const f16* __restrict__ WxT, const float* __restrict__ bias,
    f16* __restrict__ Zx, int pb, int t0, int Tc, char* smem) {
    f16 (*Ap_s)[264] = (f16(*)[264])smem;                  // 128*264*2=67584
    f16 (*Bp_s)[72]  = (f16(*)[72])(smem + 67584);         // 128*72*2 =18432
    int* tokp_s      = (int*)(smem + 86016);               // 512

    int tau  = threadIdx.x;           // 0..511
    int i0   = pb * 128;
    int wave = tau >> 6, lane = tau & 63;
    int q = lane >> 4, c = lane & 15;

    if (tau < 128) {
        int i  = i0 + tau;
        int bb = i / Tc, tr = i - bb * Tc;
        tokp_s[tau] = x[bb * T_ + t0 + tr];
    }
    __syncthreads();

    // gather A: 128 rows x 256 f32 -> fp16 LDS. 4 threads/row.
    {
        int r = tau >> 2, quarter = tau & 3;
        const float4* src =
            (const float4*)(embed + (size_t)tokp_s[r] * D_ + quarter * 64);
        f16* dst = &Ap_s[r][quarter * 64];
#pragma unroll
        for (int j = 0; j < 16; j++) {
            float4 v = src[j];
            dst[j * 4 + 0] = (f16)v.x;
            dst[j * 4 + 1] = (f16)v.y;
            dst[j * 4 + 2] = (f16)v.z;
            dst[j * 4 + 3] = (f16)v.w;
        }
    }

    for (int np = 0; np < 8; np++) {
        f32x4 acc[8];
#pragma unroll
        for (int ni = 0; ni < 8; ni++) acc[ni] = (f32x4){0.f, 0.f, 0.f, 0.f};

        for (int kt = 0; kt < 4; kt++) {
            __syncthreads();  // previous B_s consumers done (covers A_s fill)
            {
                int n = tau >> 2, qt = tau & 3;   // 128 n x 4 x 16 elems
                const f16x8* src = (const f16x8*)(WxT +
                    (size_t)(np * 128 + n) * 256 + kt * 64 + qt * 16);
                f16x8* dst = (f16x8*)&Bp_s[n][qt * 16];
                dst[0] = src[0];
                dst[1] = src[1];
            }
            __syncthreads();
#pragma unroll
            for (int s = 0; s < 2; s++) {
                f16x8 afrag =
                    *(const f16x8*)&Ap_s[wave * 16 + c][kt * 64 + s * 32 + q * 8];
#pragma unroll
                for (int ni = 0; ni < 8; ni++) {
                    f16x8 bfrag = *(const f16x8*)&Bp_s[ni * 16 + c][s * 32 + q * 8];
                    acc[ni] = __builtin_amdgcn_mfma_f32_16x16x32_f16(
                        afrag, bfrag, acc[ni], 0, 0, 0);
                }
            }
        }
#pragma unroll
        for (int ni = 0; ni < 8; ni++) {
            int n     = np * 128 + ni * 16 + c;
            int g     = n >> 8, rem = n & 255;
            int halfn = rem >> 7, colu = rem & 127;
            int np2   = halfn * 512 + colu * 4 + g;
            float bv  = bias[n];
#pragma unroll
            for (int r = 0; r < 4; r++) {
                int row = i0 + wave * 16 + q * 4 + r;
                Zx[(size_t)row * N4H + np2] = (f16)(acc[ni][r] + bv);
            }
        }
    }
}

// ---------------------------------------------------------------------------
// K2b: standalone chunk-0 Zx (512-thr producer body, 128 rows/block).
// ---------------------------------------------------------------------------
__global__ __launch_bounds__(512) void k2b_zx(
    const int* __restrict__ x, const float* __restrict__ embed,
    const f16* __restrict__ WxT, const float* __restrict__ bias,
    f16* __restrict__ Zx, int t0, int Tc) {
    __shared__ __align__(16) char smem[SMEM_BYTES];
    zx_producer(x, embed, WxT, bias, Zx, blockIdx.x, t0, Tc, smem);
}

// ---------------------------------------------------------------------------
// vu producer: attention pre-pass for one batch row b over chunk [t0v,t0v+Tc):
// vu[b][t] = tanh(outs[b][t][:] @ Womega + b_omega) . u_omega.
// outs for this chunk was completed by the PREVIOUS k3 launch.
// ---------------------------------------------------------------------------
__device__ __forceinline__ void vu_producer(
    const f16* __restrict__ outs, const f16* __restrict__ WomT,
    const float* __restrict__ b_omega, const float* __restrict__ u_omega,
    float* __restrict__ vuout, int b, int t0v, int Tc, char* smem) {
    f16 (*A_s)[264]   = (f16(*)[264])smem;                 // 64*264*2=33792
    f16 (*val_s)[132] = (f16(*)[132])(smem + 33792);       // 64*132*2=16896
    float* u_s        = (float*)(smem + 50688);            // 512

    int tau  = threadIdx.x;           // 0..511
    int wave = tau >> 6, lane = tau & 63;
    int q = lane >> 4, c = lane & 15;

    if (tau < 128) u_s[tau] = u_omega[tau];
    float bom[8];
#pragma unroll
    for (int ni = 0; ni < 8; ni++) bom[ni] = b_omega[ni * 16 + c];

    int nchap = Tc >> 6;
    for (int ch = 0; ch < nchap; ch++) {
        int t0c = t0v + ch * 64;
        __syncthreads();  // A_s/val_s reuse (+ covers u_s init)
        if (tau < 256) {  // stage 64 rows of outs
            int r = tau >> 2, seg = tau & 3;
            const f16x8* src =
                (const f16x8*)(outs + ((size_t)b * T_ + t0c + r) * H_ + seg * 64);
            f16x8* dst = (f16x8*)&A_s[r][seg * 64];
#pragma unroll
            for (int j = 0; j < 8; j++) dst[j] = src[j];
        }
        __syncthreads();
        if (tau < 256) {
            f32x4 acc[8];
#pragma unroll
            for (int ni = 0; ni < 8; ni++) acc[ni] = (f32x4){0.f, 0.f, 0.f, 0.f};
#pragma unroll
            for (int kc = 0; kc < 8; kc++) {
                f16x8 afrag = *(const f16x8*)&A_s[wave * 16 + c][kc * 32 + q * 8];
#pragma unroll
                for (int ni = 0; ni < 8; ni++) {
                    f16x8 bfrag = *(const f16x8*)(WomT +
                        (size_t)(ni * 16 + c) * 256 + kc * 32 + q * 8);
                    acc[ni] = __builtin_amdgcn_mfma_f32_16x16x32_f16(
                        afrag, bfrag, acc[ni], 0, 0, 0);
                }
            }
#pragma unroll
            for (int ni = 0; ni < 8; ni++) {
#pragma unroll
                for (int r = 0; r < 4; r++) {
                    val_s[wave * 16 + q * 4 + r][ni * 16 + c] =
                        (f16)tanh_f(acc[ni][r] + bom[ni]);
                }
            }
        }
        __syncthreads();
        if (tau < 64) {
            float s = 0.f;
#pragma unroll 8
            for (int a = 0; a < 128; a++) s += (float)val_s[tau][a] * u_s[a];
            vuout[(size_t)b * T_ + t0c + tau] = s;
        }
    }
}

// ---------------------------------------------------------------------------
// K3: persistent LSTM, split-K pipelined pair exchange (verified structure),
// fused with next-chunk Zx producer and prev-chunk vu producer families.
//
// ROUND-12 CHANGE (only one): software-pipelined poll spin. The old spin was
// fully serial per retry: check regs -> issue 2 loads -> wait full RTT
// (~700-900cy) -> check; a publish becoming visible mid-flight still cost a
// whole extra RTT. New spin: copy the in-flight poll regs, IMMEDIATELY
// re-issue the next poll, then check the copies — a fresh sample is always
// ~RTT/2 old when a miss is discovered. Correctness unchanged by
// construction: tag+payload ride in one naturally-aligned 8B atomic load
// (per-load atomic), loads retire in order (vmcnt), dangling re-issues are
// dead values overwritten before any use. Worst case = one wasted load;
// never a false positive, never a hang.
// ---------------------------------------------------------------------------
__global__ __launch_bounds__(512, 2) void k3_lstm(
    const f16* __restrict__ Zx, const f16* __restrict__ WhT,
    const int* __restrict__ seqlen, f16* __restrict__ outs,
    f16* __restrict__ Hstate, float* __restrict__ Cstate,
    u32* __restrict__ Hex, int t0, int Tc, int first, int last,
    const int* __restrict__ x, const float* __restrict__ embed,
    const f16* __restrict__ WxT, const float* __restrict__ bias,
    f16* __restrict__ ZxNext, int t0n, int npz,
    const f16* __restrict__ WomT, const float* __restrict__ b_omega,
    const float* __restrict__ u_omega, float* __restrict__ vuout, int t0v) {
    __shared__ __align__(16) char smem[SMEM_BYTES];  // union arena

    if (blockIdx.x >= 32) {
        int pid = blockIdx.x - 32;
        if (pid < npz)
            zx_producer(x, embed, WxT, bias, ZxNext, pid, t0n, Tc, smem);
        else
            vu_producer(outs, WomT, b_omega, u_omega, vuout, pid - npz, t0v,
                        Tc, smem);
        return;
    }

    f16 (*Zx_s)[16][520] = (f16(*)[16][520])smem;           // 2*16*520*2=33280
    f16 (*h_s)[16][264]  = (f16(*)[16][264])(smem + 33280); // 2*16*264*2=16896

    int tau  = threadIdx.x;
    int w    = tau >> 6, lane = tau & 63;
    int q = lane >> 4, c = lane & 15;
    int wgid = blockIdx.x;
    int pair = wgid >> 1, half = wgid & 1;
    int b0 = pair * 16;
    int u0 = half * 128, pu0 = (half ^ 1) * 128;
    int u  = u0 + w * 16 + c;   // this lane's hidden unit
    int col = w * 16 + c;       // unit index inside our 128-chunk

    u32* hexw_my = Hex + (size_t)wgid * 2 * 2048;        // [parity][16][128]
    u32* hexw_pr = Hex + (size_t)(wgid ^ 1) * 2 * 2048;

    // ---- Wh fragments pinned in AGPRs; slot s<4 = own-half K, s>=4 partner ----
    f32x4 wha[4][8];
#pragma unroll
    for (int g = 0; g < 4; g++)
#pragma unroll
        for (int s = 0; s < 8; s++) {
            int kc = (s < 4) ? (half * 4 + s) : ((half ^ 1) * 4 + (s - 4));
            f16x8 f = *(const f16x8*)(WhT +
                (size_t)(g * 256 + u0 + w * 16 + c) * 256 + kc * 32 + q * 8);
            f32x4 t = __builtin_bit_cast(f32x4, f);
            asm volatile("" : "=a"(wha[g][s]) : "0"(t));
        }

    // k-element offsets within an h_s row for the two K-halves
    int kOwn = half * 128 + q * 8;          // + kk*32
    int kPar = (half ^ 1) * 128 + q * 8;

    // ---- init h_s / cst / hprev ----
    int p0 = t0 & 1;
    if (first) {
        for (int idx = tau; idx < 2 * 16 * 264; idx += 512)
            ((f16*)h_s)[idx] = (f16)0.f;
    } else {
        for (int idx = tau; idx < 16 * 256; idx += 512) {
            int r = idx >> 8, k = idx & 255;
            h_s[p0][r][k] = Hstate[(b0 + r) * H_ + k];
        }
    }

    float cst[4];
    f16   hprev[4];
    int   sl[4];
#pragma unroll
    for (int r = 0; r < 4; r++) {
        int row = q * 4 + r;
        cst[r]   = first ? 0.f : Cstate[(b0 + row) * H_ + u];
        hprev[r] = first ? (f16)0.f : Hstate[(b0 + row) * H_ + u];
        sl[r]    = seqlen[b0 + row];
    }

    // Zx staging geometry: thread stages 32 B of row (tau>>5), cols (tau&31)*16
    int r_st = tau >> 5;
    int cc   = (tau & 31) * 16;
    const f16* zxrow = Zx + ((size_t)(b0 + r_st) * Tc) * N4H + half * 512 + cc;

    // prologue: fill Zx_s for step 0
    {
        const f16x8* src = (const f16x8*)zxrow;
        f16x8* dst = (f16x8*)&Zx_s[p0][r_st][cc];
        dst[0] = src[0];
        dst[1] = src[1];
    }
    // partner-merge geometry: thread handles 4 words: row tau>>5, cols (tau&31)*4
    int rr = tau >> 5;
    int uu = (tau & 31) * 4;

    __syncthreads();  // prologue: full drain once is fine

    // prologue: own-half partial MFMA from h_s[p0]
    f32x4 accO[4];
#pragma unroll
    for (int g = 0; g < 4; g++) accO[g] = (f32x4){0.f, 0.f, 0.f, 0.f};
#pragma unroll
    for (int kk = 0; kk < 4; kk++) {
        f16x8 afrag = *(const f16x8*)&h_s[p0][c][kOwn + kk * 32];
#pragma unroll
        for (int g = 0; g < 4; g++) MFMA_A(accO[g], afrag, wha[g][kk]);
    }

    u64 vp0 = 0, vp1 = 0;  // in-flight partner poll payload

    for (int tt = 0; tt < Tc; tt++) {
        int t   = t0 + tt;
        int cur = t & 1, nxt = cur ^ 1;

        // Zx prefetch for t+1 (max latency cover: consumed end of iteration)
        int tn = (tt + 1 < Tc) ? tt + 1 : tt;
        const f16x8* psrc = (const f16x8*)(zxrow + (size_t)tn * N4H);
        f16x8 z0 = psrc[0];
        f16x8 z1 = psrc[1];

        // poll + merge partner half of h_t (skip at chunk start: h_s complete)
        // Pipelined spin: check the PREVIOUS sample while the NEXT is already
        // in flight — a miss is discovered with a half-RTT-old refill pending.
        if (tt > 0) {
            u32 tagp = (u32)(t & 0xffff);
            const u64* pp = (const u64*)&hexw_pr[cur * 2048 + rr * 128 + uu];
            for (;;) {
                u64 w0 = vp0, w1 = vp1;   // compiler waits in-flight loads
                vp0 = __hip_atomic_load(pp + 0, __ATOMIC_RELAXED,
                                        __HIP_MEMORY_SCOPE_AGENT);
                vp1 = __hip_atomic_load(pp + 1, __ATOMIC_RELAXED,
                                        __HIP_MEMORY_SCOPE_AGENT);
                if (((u32)(w0 >> 16) & 0xffffu) == tagp &&
                    ((u32)(w0 >> 48)) == tagp &&
                    ((u32)(w1 >> 16) & 0xffffu) == tagp &&
                    ((u32)(w1 >> 48)) == tagp) {
                    u64 hw = (u64)(w0 & 0xffff) |
                             (((w0 >> 32) & 0xffff) << 16) |
                             ((w1 & 0xffff) << 32) |
                             (((w1 >> 32) & 0xffff) << 48);
                    *(u64*)&h_s[cur][rr][pu0 + uu] = hw;
                    break;
                }
            }
        }
        LGKM_BARRIER();  // partner half visible; h_s[cur] complete

        // partner-half K MFMA (slots 4-7) -> full pre-activations in accO
#pragma unroll
        for (int kk = 0; kk < 4; kk++) {
            f16x8 afrag = *(const f16x8*)&h_s[cur][c][kPar + kk * 32];
#pragma unroll
            for (int g = 0; g < 4; g++) MFMA_A(accO[g], afrag, wha[g][4 + kk]);
        }

        // gates (C layout: col=c, row=q*4+r); publish own h with tag t+1
        u32 tag = (u32)((t + 1) & 0xffff);
        f16 ovals[4];
#pragma unroll
        for (int r = 0; r < 4; r++) {
            int row = q * 4 + r;
            f16x4 zv = *(const f16x4*)&Zx_s[cur][row][col * 4];
            float zi = accO[0][r] + (float)zv[0];
            float zj = accO[1][r] + (float)zv[1];
            float zf = accO[2][r] + (float)zv[2];
            float zo = accO[3][r] + (float)zv[3];
            float ig = sigmoid_f(zi);
            float jg = tanh_f(zj);
            float fg = sigmoid_f(zf + 1.f);
            float og = sigmoid_f(zo);
            float cn = cst[r] * fg + ig * jg;
            float hn = tanh_f(cn) * og;
            bool  m  = (t < sl[r]);
            cst[r]   = m ? cn : cst[r];
            f16 hkeep = m ? (f16)hn : hprev[r];
            hprev[r]  = hkeep;
            h_s[nxt][row][u] = hkeep;
            u32 word = (tag << 16) |
                       (u32)(unsigned short)__builtin_bit_cast(short, hkeep);
            __hip_atomic_store(&hexw_my[nxt * 2048 + row * 128 + col], word,
                               __ATOMIC_RELAXED, __HIP_MEMORY_SCOPE_AGENT);
            ovals[r] = m ? (f16)hn : (f16)0.f;
        }

        // consume Zx prefetch into other parity
        {
            f16x8* dst = (f16x8*)&Zx_s[nxt][r_st][cc];
            dst[0] = z0;
            dst[1] = z1;
        }

        // outs stores
#pragma unroll
        for (int r = 0; r < 4; r++)
            outs[((size_t)(b0 + q * 4 + r) * T_ + t) * H_ + u] = ovals[r];

        // issue partner polls for h_{t+1} LAST: sample L3 late (past the
        // partner's publish-to-L3 latency); stay in flight across the barrier.
        {
            const u64* pp2 = (const u64*)&hexw_pr[nxt * 2048 + rr * 128 + uu];
            vp0 = __hip_atomic_load(pp2 + 0, __ATOMIC_RELAXED,
                                    __HIP_MEMORY_SCOPE_AGENT);
            vp1 = __hip_atomic_load(pp2 + 1, __ATOMIC_RELAXED,
                                    __HIP_MEMORY_SCOPE_AGENT);
        }

        LGKM_BARRIER();  // own half of h_s[nxt] + Zx_s[nxt] ready

        // own-half K MFMA for step t+1 (slots 0-3) — covers exchange RTT
#pragma unroll
        for (int g = 0; g < 4; g++) accO[g] = (f32x4){0.f, 0.f, 0.f, 0.f};
#pragma unroll
        for (int kk = 0; kk < 4; kk++) {
            f16x8 afrag = *(const f16x8*)&h_s[nxt][c][kOwn + kk * 32];
#pragma unroll
            for (int g = 0; g < 4; g++) MFMA_A(accO[g], afrag, wha[g][kk]);
        }
    }

    if (!last) {
        int parity = (t0 + Tc) & 1;
        for (int idx = tau; idx < 16 * 128; idx += 512) {
            int r = idx >> 7, k = u0 + (idx & 127);
            Hstate[(b0 + r) * H_ + k] = h_s[parity][r][k];
        }
#pragma unroll
        for (int r = 0; r < 4; r++)
            Cstate[(b0 + q * 4 + r) * H_ + u] = cst[r];
    }
}

// ---------------------------------------------------------------------------
// K4: attention + head, 512 threads per batch row (verified round 7).
// vu for t < tstart is precomputed by fused vu producers; the last chunk's
// chapters run here (tau<256 guard, identical math). The T=512 weighted sum
// is split across two 256-thread groups and combined through LDS.
// ---------------------------------------------------------------------------
__global__ __launch_bounds__(512) void k4_attn(
    const f16* __restrict__ outs, const f16* __restrict__ WomT,
    const float* __restrict__ b_omega, const float* __restrict__ u_omega,
    const float* __restrict__ w, const float* __restrict__ bfin,
    const float* __restrict__ vuin, int tstart, float* __restrict__ out) {
    __shared__ __align__(16) f16 A_s[64][264];
    __shared__ __align__(16) f16 val_s[64][132];
    __shared__ float u_s[128];
    __shared__ float vu_s[512];
    __shared__ float red0[512], red1[512];

    int b = blockIdx.x, tau = threadIdx.x;  // 0..511
    int wave = tau >> 6, lane = tau & 63;
    int q = lane >> 4, c = lane & 15;

    if (tau < 128) u_s[tau] = u_omega[tau];
    float bom[8];
#pragma unroll
    for (int ni = 0; ni < 8; ni++) bom[ni] = b_omega[ni * 16 + c];

    // fill precomputed vu (tstart is a multiple of 64; 0 disables)
    for (int t = tau; t < tstart; t += 512) vu_s[t] = vuin[(size_t)b * T_ + t];

    for (int ch = tstart >> 6; ch < 8; ch++) {
        int t0c = ch * 64;
        __syncthreads();  // protects A_s/val_s reuse (+ covers u_s/vu fill)
        if (tau < 256) {  // stage 64 rows of outs
            int r = tau >> 2, seg = tau & 3;
            const f16x8* src =
                (const f16x8*)(outs + ((size_t)b * T_ + t0c + r) * H_ + seg * 64);
            f16x8* dst = (f16x8*)&A_s[r][seg * 64];
#pragma unroll
            for (int j = 0; j < 8; j++) dst[j] = src[j];
        }
        __syncthreads();
        if (tau < 256) {
            f32x4 acc[8];
#pragma unroll
            for (int ni = 0; ni < 8; ni++) acc[ni] = (f32x4){0.f, 0.f, 0.f, 0.f};
#pragma unroll
            for (int kc = 0; kc < 8; kc++) {
                f16x8 afrag = *(const f16x8*)&A_s[wave * 16 + c][kc * 32 + q * 8];
#pragma unroll
                for (int ni = 0; ni < 8; ni++) {
                    f16x8 bfrag = *(const f16x8*)(WomT +
                        (size_t)(ni * 16 + c) * 256 + kc * 32 + q * 8);
                    acc[ni] = __builtin_amdgcn_mfma_f32_16x16x32_f16(
                        afrag, bfrag, acc[ni], 0, 0, 0);
                }
            }
#pragma unroll
            for (int ni = 0; ni < 8; ni++) {
#pragma unroll
                for (int r = 0; r < 4; r++) {
                    val_s[wave * 16 + q * 4 + r][ni * 16 + c] =
                        (f16)tanh_f(acc[ni][r] + bom[ni]);
                }
            }
        }
        __syncthreads();
        if (tau < 64) {
            float s = 0.f;
#pragma unroll 8
            for (int a = 0; a < 128; a++) s += (float)val_s[tau][a] * u_s[a];
            vu_s[t0c + tau] = s;
        }
    }
    __syncthreads();

    // softmax over T=512, one element per thread
    red0[tau] = vu_s[tau];
    __syncthreads();
    for (int s = 256; s > 0; s >>= 1) {
        if (tau < s) red0[tau] = fmaxf(red0[tau], red0[tau + s]);
        __syncthreads();
    }
    float mx = red0[0];
    __syncthreads();
    float e = __expf(vu_s[tau] - mx);
    red0[tau] = e;
    __syncthreads();
    for (int s = 256; s > 0; s >>= 1) {
        if (tau < s) red0[tau] += red0[tau + s];
        __syncthreads();
    }
    float inv = 1.f / red0[0];
    __syncthreads();
    vu_s[tau] = e * inv;
    __syncthreads();

    // last[h] = sum_t alpha[t]*outs[b][t][h]; t split across two 256-thr groups
    int h = tau & 255, tg = tau >> 8;
    float lastv = 0.f;
    {
        const f16* orow = outs + ((size_t)b * T_ + tg * 256) * H_ + h;
        const float* al = &vu_s[tg * 256];
#pragma unroll 4
        for (int t = 0; t < 256; t++)
            lastv += al[t] * (float)orow[(size_t)t * H_];
    }
    red0[tau] = lastv;
    __syncthreads();
    float lsum = (tau < 256) ? red0[tau] + red0[tau + 256] : 0.f;
    __syncthreads();  // red0 reuse below

    // logits + 2-class softmax
    red0[tau] = (tau < 256) ? lsum * w[h * 2 + 0] : 0.f;
    red1[tau] = (tau < 256) ? lsum * w[h * 2 + 1] : 0.f;
    __syncthreads();
    for (int s = 256; s > 0; s >>= 1) {
        if (tau < s) {
            red0[tau] += red0[tau + s];
            red1[tau] += red1[tau + s];
        }
        __syncthreads();
    }
    if (tau == 0) {
        float l0 = red0[0] + bfin[0], l1 = red1[0] + bfin[1];
        float mm = fmaxf(l0, l1);
        float a0 = __expf(l0 - mm), a1 = __expf(l1 - mm);
        float den = a0 + a1;
        out[b * 2 + 0] = a0 / den;
        out[b * 2 + 1] = a1 / den;
    }
}

// ---------------------------------------------------------------------------
extern "C" void kernel_launch(void* const* d_in, const int* in_sizes, int n_in,
                              void* d_out, int out_size, void* d_ws,
                              size_t ws_size, hipStream_t stream) {
    const int*   x           = (const int*)d_in[0];
    const float* embed       = (const float*)d_in[1];
    const float* lstm_kernel = (const float*)d_in[2];
    const float* lstm_bias   = (const float*)d_in[3];
    const float* w_omega     = (const float*)d_in[4];
    const float* b_omega     = (const float*)d_in[5];
    const float* u_omega     = (const float*)d_in[6];
    const float* w           = (const float*)d_in[7];
    const float* bfin        = (const float*)d_in[8];
    float*       out         = (float*)d_out;

    char* ws = (char*)d_ws;
    f16*   WxT    = (f16*)(ws + 0);              //  524288 B
    f16*   WhT    = (f16*)(ws + 524288);         //  524288 B
    f16*   WomT   = (f16*)(ws + 1048576);        //   65536 B
    int*   seqlen = (int*)(ws + 1114112);        //    1024 B
    f16*   Hstate = (f16*)(ws + 1115136);        //  131072 B
    float* Cstate = (float*)(ws + 1246208);      //  262144 B
    u32*   Hex    = (u32*)(ws + 1508352);        //  524288 B (32 wg x 16KB)
    float* vu     = (float*)(ws + 2032640);      //  524288 B (B x T f32)
    f16*   outs   = (f16*)(ws + 2556928);        // 67108864 B

    // Zx double buffer for producer-fusion: need fixed + 2 chunks <= ws.
    const size_t fixed = 2556928ull + 67108864ull;
    int nch = 1;
    while (nch < 16 && fixed + 2ull * (268435456ull / (size_t)nch) > ws_size)
        nch <<= 1;
    int Tc = T_ / nch;
    size_t chunkB = 268435456ull / (size_t)nch;
    f16* ZxA = (f16*)(ws + fixed);
    f16* ZxB = (f16*)(ws + fixed + chunkB);  // unused when nch == 1

    // vu fusion requires chunk length a multiple of the 64-step chapter size
    int vuEnable = (Tc % 64 == 0) && (nch >= 2);
    int tstart   = vuEnable ? (nch - 1) * Tc : 0;

    // k0 (weights) + seqlen fused in one launch
    k0_convert<<<N4H + A_ + B_, 256, 0, stream>>>(lstm_kernel, w_omega, WxT,
                                                  WhT, WomT, x, seqlen);
    // chunk 0's Zx standalone (512-thr, 128 rows/block)
    k2b_zx<<<(B_ * Tc) / 128, 512, 0, stream>>>(x, embed, WxT, lstm_bias, ZxA,
                                                0, Tc);
    for (int chk = 0; chk < nch; chk++) {
        int  t0  = chk * Tc;
        f16* zc  = (chk & 1) ? ZxB : ZxA;
        f16* zn  = (chk & 1) ? ZxA : ZxB;
        int  npz = (chk + 1 < nch) ? (B_ * Tc) / 128 : 0;  // Zx producer blocks
        int  nv  = (vuEnable && chk >= 1) ? B_ : 0;        // vu producer blocks
        int  t0n = (chk + 1) * Tc;
        int  t0v = (chk - 1) * Tc;
        k3_lstm<<<32 + npz + nv, 512, 0, stream>>>(
            zc, WhT, seqlen, outs, Hstate, Cstate, Hex, t0, Tc,
            chk == 0 ? 1 : 0, chk == nch - 1 ? 1 : 0,
            x, embed, WxT, lstm_bias, zn, t0n, npz,
            WomT, b_omega, u_omega, vu, t0v);
    }
    k4_attn<<<256, 512, 0, stream>>>(outs, WomT, b_omega, u_omega, w, bfin,
                                     vu, tstart, out);
}

// Round 13
// 1434.817 us; speedup vs baseline: 1.0939x; 1.0939x over previous
//
#include <hip/hip_runtime.h>
#include <hip/hip_bf16.h>
#include <cstdint>
#include <cstddef>

typedef _Float16 f16;
typedef _Float16 f16x8 __attribute__((ext_vector_type(8)));
typedef _Float16 f16x4 __attribute__((ext_vector_type(4)));
typedef float f32x4 __attribute__((ext_vector_type(4)));
typedef unsigned long long u64;
typedef unsigned int u32;

#define B_   256
#define T_   512
#define V_   50000
#define D_   256
#define H_   256
#define A_   128
#define N4H  1024

__device__ __forceinline__ float sigmoid_f(float x) {
    return __builtin_amdgcn_rcpf(1.f + __expf(-x));
}
__device__ __forceinline__ float tanh_f(float x) {
    float e = __expf(-2.f * fabsf(x));
    float t = 1.f - 2.f * e * __builtin_amdgcn_rcpf(1.f + e);
    return copysignf(t, x);
}

// asm MFMA with B operand taken straight from AGPRs (no accvgpr_read moves)
#define MFMA_A(accv, afragv, bfraga)                                         \
    asm volatile("v_mfma_f32_16x16x32_f16 %0, %1, %2, %0"                    \
                 : "+v"(accv) : "v"(afragv), "a"(bfraga))

// LDS-drain-only barrier: keeps global loads/stores (polls!) in flight
// across the barrier; only LDS ordering is enforced. Verified round 4.
#define LGKM_BARRIER()                                                       \
    do {                                                                     \
        asm volatile("s_waitcnt lgkmcnt(0)" ::: "memory");                   \
        __builtin_amdgcn_sched_barrier(0);                                   \
        __builtin_amdgcn_s_barrier();                                        \
        __builtin_amdgcn_sched_barrier(0);                                   \
    } while (0)

// ---------------------------------------------------------------------------
// K0: weight transpose + fp32->fp16 cast, fused with seqlen (blocks >= 1152).
// ---------------------------------------------------------------------------
__global__ __launch_bounds__(256) void k0_convert(
    const float* __restrict__ lstm_kernel, const float* __restrict__ w_omega,
    f16* __restrict__ WxT, f16* __restrict__ WhT, f16* __restrict__ WomT,
    const int* __restrict__ x, int* __restrict__ seqlen) {
    __shared__ int red[256];
    int blk = blockIdx.x;
    int tau = threadIdx.x;  // 0..255 (= k / h index)
    if (blk < N4H) {
        int n = blk;
        WxT[n * 256 + tau] = (f16)lstm_kernel[(size_t)tau * N4H + n];
        WhT[n * 256 + tau] = (f16)lstm_kernel[(size_t)(256 + tau) * N4H + n];
    } else if (blk < N4H + A_) {
        int a = blk - N4H;  // 0..127
        WomT[a * 256 + tau] = (f16)w_omega[(size_t)tau * A_ + a];
    } else {
        // seqlen for batch row b
        int b = blk - (N4H + A_);
        int cnt = (x[b * T_ + tau] != 0) + (x[b * T_ + tau + 256] != 0);
        red[tau] = cnt;
        __syncthreads();
        for (int s = 128; s > 0; s >>= 1) {
            if (tau < s) red[tau] += red[tau + s];
            __syncthreads();
        }
        if (tau == 0) seqlen[b] = red[0];
    }
}

// ===========================================================================
// Shared LDS arena size (union across LSTM / Zx producer / vu producer).
// ===========================================================================
#define SMEM_BYTES 87040

// ---------------------------------------------------------------------------
// Zx producer, 512-thread (128 rows/block), for chunk starting at t0.
// Zx column layout is half-split AND gate-interleaved:
// n = g*256 + half*128 + colu -> n'' = half*512 + colu*4 + g
// so the LSTM reads {i,j,f,o} for one unit as ONE ds_read_b64.
// ---------------------------------------------------------------------------
__device__ __forceinline__ void zx_producer(
    const int* __restrict__ x, const float* __restrict__ embed,
    const f16* __restrict__ WxT, const float* __restrict__ bias,
    f16* __restrict__ Zx, int pb, int t0, int Tc, char* smem) {
    f16 (*Ap_s)[264] = (f16(*)[264])smem;                  // 128*264*2=67584
    f16 (*Bp_s)[72]  = (f16(*)[72])(smem + 67584);         // 128*72*2 =18432
    int* tokp_s      = (int*)(smem + 86016);               // 512

    int tau  = threadIdx.x;           // 0..511
    int i0   = pb * 128;
    int wave = tau >> 6, lane = tau & 63;
    int q = lane >> 4, c = lane & 15;

    if (tau < 128) {
        int i  = i0 + tau;
        int bb = i / Tc, tr = i - bb * Tc;
        tokp_s[tau] = x[bb * T_ + t0 + tr];
    }
    __syncthreads();

    // gather A: 128 rows x 256 f32 -> fp16 LDS. 4 threads/row.
    {
        int r = tau >> 2, quarter = tau & 3;
        const float4* src =
            (const float4*)(embed + (size_t)tokp_s[r] * D_ + quarter * 64);
        f16* dst = &Ap_s[r][quarter * 64];
#pragma unroll
        for (int j = 0; j < 16; j++) {
            float4 v = src[j];
            dst[j * 4 + 0] = (f16)v.x;
            dst[j * 4 + 1] = (f16)v.y;
            dst[j * 4 + 2] = (f16)v.z;
            dst[j * 4 + 3] = (f16)v.w;
        }
    }

    for (int np = 0; np < 8; np++) {
        f32x4 acc[8];
#pragma unroll
        for (int ni = 0; ni < 8; ni++) acc[ni] = (f32x4){0.f, 0.f, 0.f, 0.f};

        for (int kt = 0; kt < 4; kt++) {
            __syncthreads();  // previous B_s consumers done (covers A_s fill)
            {
                int n = tau >> 2, qt = tau & 3;   // 128 n x 4 x 16 elems
                const f16x8* src = (const f16x8*)(WxT +
                    (size_t)(np * 128 + n) * 256 + kt * 64 + qt * 16);
                f16x8* dst = (f16x8*)&Bp_s[n][qt * 16];
                dst[0] = src[0];
                dst[1] = src[1];
            }
            __syncthreads();
#pragma unroll
            for (int s = 0; s < 2; s++) {
                f16x8 afrag =
                    *(const f16x8*)&Ap_s[wave * 16 + c][kt * 64 + s * 32 + q * 8];
#pragma unroll
                for (int ni = 0; ni < 8; ni++) {
                    f16x8 bfrag = *(const f16x8*)&Bp_s[ni * 16 + c][s * 32 + q * 8];
                    acc[ni] = __builtin_amdgcn_mfma_f32_16x16x32_f16(
                        afrag, bfrag, acc[ni], 0, 0, 0);
                }
            }
        }
#pragma unroll
        for (int ni = 0; ni < 8; ni++) {
            int n     = np * 128 + ni * 16 + c;
            int g     = n >> 8, rem = n & 255;
            int halfn = rem >> 7, colu = rem & 127;
            int np2   = halfn * 512 + colu * 4 + g;
            float bv  = bias[n];
#pragma unroll
            for (int r = 0; r < 4; r++) {
                int row = i0 + wave * 16 + q * 4 + r;
                Zx[(size_t)row * N4H + np2] = (f16)(acc[ni][r] + bv);
            }
        }
    }
}

// ---------------------------------------------------------------------------
// K2b: standalone chunk-0 Zx (512-thr producer body, 128 rows/block).
// ---------------------------------------------------------------------------
__global__ __launch_bounds__(512) void k2b_zx(
    const int* __restrict__ x, const float* __restrict__ embed,
    const f16* __restrict__ WxT, const float* __restrict__ bias,
    f16* __restrict__ Zx, int t0, int Tc) {
    __shared__ __align__(16) char smem[SMEM_BYTES];
    zx_producer(x, embed, WxT, bias, Zx, blockIdx.x, t0, Tc, smem);
}

// ---------------------------------------------------------------------------
// vu producer: attention pre-pass for one batch row b over chunk [t0v,t0v+Tc):
// vu[b][t] = tanh(outs[b][t][:] @ Womega + b_omega) . u_omega.
// outs for this chunk was completed by the PREVIOUS k3 launch.
// ---------------------------------------------------------------------------
__device__ __forceinline__ void vu_producer(
    const f16* __restrict__ outs, const f16* __restrict__ WomT,
    const float* __restrict__ b_omega, const float* __restrict__ u_omega,
    float* __restrict__ vuout, int b, int t0v, int Tc, char* smem) {
    f16 (*A_s)[264]   = (f16(*)[264])smem;                 // 64*264*2=33792
    f16 (*val_s)[132] = (f16(*)[132])(smem + 33792);       // 64*132*2=16896
    float* u_s        = (float*)(smem + 50688);            // 512

    int tau  = threadIdx.x;           // 0..511
    int wave = tau >> 6, lane = tau & 63;
    int q = lane >> 4, c = lane & 15;

    if (tau < 128) u_s[tau] = u_omega[tau];
    float bom[8];
#pragma unroll
    for (int ni = 0; ni < 8; ni++) bom[ni] = b_omega[ni * 16 + c];

    int nchap = Tc >> 6;
    for (int ch = 0; ch < nchap; ch++) {
        int t0c = t0v + ch * 64;
        __syncthreads();  // A_s/val_s reuse (+ covers u_s init)
        if (tau < 256) {  // stage 64 rows of outs
            int r = tau >> 2, seg = tau & 3;
            const f16x8* src =
                (const f16x8*)(outs + ((size_t)b * T_ + t0c + r) * H_ + seg * 64);
            f16x8* dst = (f16x8*)&A_s[r][seg * 64];
#pragma unroll
            for (int j = 0; j < 8; j++) dst[j] = src[j];
        }
        __syncthreads();
        if (tau < 256) {
            f32x4 acc[8];
#pragma unroll
            for (int ni = 0; ni < 8; ni++) acc[ni] = (f32x4){0.f, 0.f, 0.f, 0.f};
#pragma unroll
            for (int kc = 0; kc < 8; kc++) {
                f16x8 afrag = *(const f16x8*)&A_s[wave * 16 + c][kc * 32 + q * 8];
#pragma unroll
                for (int ni = 0; ni < 8; ni++) {
                    f16x8 bfrag = *(const f16x8*)(WomT +
                        (size_t)(ni * 16 + c) * 256 + kc * 32 + q * 8);
                    acc[ni] = __builtin_amdgcn_mfma_f32_16x16x32_f16(
                        afrag, bfrag, acc[ni], 0, 0, 0);
                }
            }
#pragma unroll
            for (int ni = 0; ni < 8; ni++) {
#pragma unroll
                for (int r = 0; r < 4; r++) {
                    val_s[wave * 16 + q * 4 + r][ni * 16 + c] =
                        (f16)tanh_f(acc[ni][r] + bom[ni]);
                }
            }
        }
        __syncthreads();
        if (tau < 64) {
            float s = 0.f;
#pragma unroll 8
            for (int a = 0; a < 128; a++) s += (float)val_s[tau][a] * u_s[a];
            vuout[(size_t)b * T_ + t0c + tau] = s;
        }
    }
}

// ---------------------------------------------------------------------------
// K3: persistent LSTM, split-K pipelined pair exchange (verified structure,
// LSTM body untouched since round 5), fused with next-chunk Zx producer and
// prev-chunk vu producer block families. LSTM blocks are blockIdx 0..31 ->
// resident first; producers never wait on anything -> no scheduling order
// can deadlock. The 2-CU pair split is register-optimal: Wh fp16 = 512KB =
// the CU's entire register file, so a single-WG exchange-free design cannot
// fit. The serial poll spin is retry-optimal: both the L2 fast-path (r1),
// barrier-drain removal (r4), poll-late (r5), phase-split (r9), and
// pipelined-poll (r12) variants were neutral or regressions — the step time
// is pure cross-die publish->visible latency through the L3 coherence
// point, already overlapped with all available compute.
// ---------------------------------------------------------------------------
__global__ __launch_bounds__(512, 2) void k3_lstm(
    const f16* __restrict__ Zx, const f16* __restrict__ WhT,
    const int* __restrict__ seqlen, f16* __restrict__ outs,
    f16* __restrict__ Hstate, float* __restrict__ Cstate,
    u32* __restrict__ Hex, int t0, int Tc, int first, int last,
    const int* __restrict__ x, const float* __restrict__ embed,
    const f16* __restrict__ WxT, const float* __restrict__ bias,
    f16* __restrict__ ZxNext, int t0n, int npz,
    const f16* __restrict__ WomT, const float* __restrict__ b_omega,
    const float* __restrict__ u_omega, float* __restrict__ vuout, int t0v) {
    __shared__ __align__(16) char smem[SMEM_BYTES];  // union arena

    if (blockIdx.x >= 32) {
        int pid = blockIdx.x - 32;
        if (pid < npz)
            zx_producer(x, embed, WxT, bias, ZxNext, pid, t0n, Tc, smem);
        else
            vu_producer(outs, WomT, b_omega, u_omega, vuout, pid - npz, t0v,
                        Tc, smem);
        return;
    }

    f16 (*Zx_s)[16][520] = (f16(*)[16][520])smem;           // 2*16*520*2=33280
    f16 (*h_s)[16][264]  = (f16(*)[16][264])(smem + 33280); // 2*16*264*2=16896

    int tau  = threadIdx.x;
    int w    = tau >> 6, lane = tau & 63;
    int q = lane >> 4, c = lane & 15;
    int wgid = blockIdx.x;
    int pair = wgid >> 1, half = wgid & 1;
    int b0 = pair * 16;
    int u0 = half * 128, pu0 = (half ^ 1) * 128;
    int u  = u0 + w * 16 + c;   // this lane's hidden unit
    int col = w * 16 + c;       // unit index inside our 128-chunk

    u32* hexw_my = Hex + (size_t)wgid * 2 * 2048;        // [parity][16][128]
    u32* hexw_pr = Hex + (size_t)(wgid ^ 1) * 2 * 2048;

    // ---- Wh fragments pinned in AGPRs; slot s<4 = own-half K, s>=4 partner ----
    f32x4 wha[4][8];
#pragma unroll
    for (int g = 0; g < 4; g++)
#pragma unroll
        for (int s = 0; s < 8; s++) {
            int kc = (s < 4) ? (half * 4 + s) : ((half ^ 1) * 4 + (s - 4));
            f16x8 f = *(const f16x8*)(WhT +
                (size_t)(g * 256 + u0 + w * 16 + c) * 256 + kc * 32 + q * 8);
            f32x4 t = __builtin_bit_cast(f32x4, f);
            asm volatile("" : "=a"(wha[g][s]) : "0"(t));
        }

    // k-element offsets within an h_s row for the two K-halves
    int kOwn = half * 128 + q * 8;          // + kk*32
    int kPar = (half ^ 1) * 128 + q * 8;

    // ---- init h_s / cst / hprev ----
    int p0 = t0 & 1;
    if (first) {
        for (int idx = tau; idx < 2 * 16 * 264; idx += 512)
            ((f16*)h_s)[idx] = (f16)0.f;
    } else {
        for (int idx = tau; idx < 16 * 256; idx += 512) {
            int r = idx >> 8, k = idx & 255;
            h_s[p0][r][k] = Hstate[(b0 + r) * H_ + k];
        }
    }

    float cst[4];
    f16   hprev[4];
    int   sl[4];
#pragma unroll
    for (int r = 0; r < 4; r++) {
        int row = q * 4 + r;
        cst[r]   = first ? 0.f : Cstate[(b0 + row) * H_ + u];
        hprev[r] = first ? (f16)0.f : Hstate[(b0 + row) * H_ + u];
        sl[r]    = seqlen[b0 + row];
    }

    // Zx staging geometry: thread stages 32 B of row (tau>>5), cols (tau&31)*16
    int r_st = tau >> 5;
    int cc   = (tau & 31) * 16;
    const f16* zxrow = Zx + ((size_t)(b0 + r_st) * Tc) * N4H + half * 512 + cc;

    // prologue: fill Zx_s for step 0
    {
        const f16x8* src = (const f16x8*)zxrow;
        f16x8* dst = (f16x8*)&Zx_s[p0][r_st][cc];
        dst[0] = src[0];
        dst[1] = src[1];
    }
    // partner-merge geometry: thread handles 4 words: row tau>>5, cols (tau&31)*4
    int rr = tau >> 5;
    int uu = (tau & 31) * 4;

    __syncthreads();  // prologue: full drain once is fine

    // prologue: own-half partial MFMA from h_s[p0]
    f32x4 accO[4];
#pragma unroll
    for (int g = 0; g < 4; g++) accO[g] = (f32x4){0.f, 0.f, 0.f, 0.f};
#pragma unroll
    for (int kk = 0; kk < 4; kk++) {
        f16x8 afrag = *(const f16x8*)&h_s[p0][c][kOwn + kk * 32];
#pragma unroll
        for (int g = 0; g < 4; g++) MFMA_A(accO[g], afrag, wha[g][kk]);
    }

    u64 vp0 = 0, vp1 = 0;  // in-flight partner poll payload

    for (int tt = 0; tt < Tc; tt++) {
        int t   = t0 + tt;
        int cur = t & 1, nxt = cur ^ 1;

        // Zx prefetch for t+1 (max latency cover: consumed end of iteration)
        int tn = (tt + 1 < Tc) ? tt + 1 : tt;
        const f16x8* psrc = (const f16x8*)(zxrow + (size_t)tn * N4H);
        f16x8 z0 = psrc[0];
        f16x8 z1 = psrc[1];

        // poll + merge partner half of h_t (skip at chunk start: h_s complete)
        if (tt > 0) {
            u32 tagp = (u32)(t & 0xffff);
            const u64* pp = (const u64*)&hexw_pr[cur * 2048 + rr * 128 + uu];
            while (((u32)(vp0 >> 16) & 0xffffu) != tagp ||
                   ((u32)(vp0 >> 48)) != tagp ||
                   ((u32)(vp1 >> 16) & 0xffffu) != tagp ||
                   ((u32)(vp1 >> 48)) != tagp) {
                vp0 = __hip_atomic_load(pp + 0, __ATOMIC_RELAXED,
                                        __HIP_MEMORY_SCOPE_AGENT);
                vp1 = __hip_atomic_load(pp + 1, __ATOMIC_RELAXED,
                                        __HIP_MEMORY_SCOPE_AGENT);
            }
            u64 hw = (u64)(vp0 & 0xffff) | (((vp0 >> 32) & 0xffff) << 16) |
                     ((vp1 & 0xffff) << 32) | (((vp1 >> 32) & 0xffff) << 48);
            *(u64*)&h_s[cur][rr][pu0 + uu] = hw;
        }
        LGKM_BARRIER();  // partner half visible; h_s[cur] complete

        // partner-half K MFMA (slots 4-7) -> full pre-activations in accO
#pragma unroll
        for (int kk = 0; kk < 4; kk++) {
            f16x8 afrag = *(const f16x8*)&h_s[cur][c][kPar + kk * 32];
#pragma unroll
            for (int g = 0; g < 4; g++) MFMA_A(accO[g], afrag, wha[g][4 + kk]);
        }

        // gates (C layout: col=c, row=q*4+r); publish own h with tag t+1
        u32 tag = (u32)((t + 1) & 0xffff);
        f16 ovals[4];
#pragma unroll
        for (int r = 0; r < 4; r++) {
            int row = q * 4 + r;
            f16x4 zv = *(const f16x4*)&Zx_s[cur][row][col * 4];
            float zi = accO[0][r] + (float)zv[0];
            float zj = accO[1][r] + (float)zv[1];
            float zf = accO[2][r] + (float)zv[2];
            float zo = accO[3][r] + (float)zv[3];
            float ig = sigmoid_f(zi);
            float jg = tanh_f(zj);
            float fg = sigmoid_f(zf + 1.f);
            float og = sigmoid_f(zo);
            float cn = cst[r] * fg + ig * jg;
            float hn = tanh_f(cn) * og;
            bool  m  = (t < sl[r]);
            cst[r]   = m ? cn : cst[r];
            f16 hkeep = m ? (f16)hn : hprev[r];
            hprev[r]  = hkeep;
            h_s[nxt][row][u] = hkeep;
            u32 word = (tag << 16) |
                       (u32)(unsigned short)__builtin_bit_cast(short, hkeep);
            __hip_atomic_store(&hexw_my[nxt * 2048 + row * 128 + col], word,
                               __ATOMIC_RELAXED, __HIP_MEMORY_SCOPE_AGENT);
            ovals[r] = m ? (f16)hn : (f16)0.f;
        }

        // consume Zx prefetch into other parity
        {
            f16x8* dst = (f16x8*)&Zx_s[nxt][r_st][cc];
            dst[0] = z0;
            dst[1] = z1;
        }

        // outs stores
#pragma unroll
        for (int r = 0; r < 4; r++)
            outs[((size_t)(b0 + q * 4 + r) * T_ + t) * H_ + u] = ovals[r];

        // issue partner polls for h_{t+1} LAST: sample L3 late (past the
        // partner's publish-to-L3 latency); stay in flight across the barrier.
        {
            const u64* pp2 = (const u64*)&hexw_pr[nxt * 2048 + rr * 128 + uu];
            vp0 = __hip_atomic_load(pp2 + 0, __ATOMIC_RELAXED,
                                    __HIP_MEMORY_SCOPE_AGENT);
            vp1 = __hip_atomic_load(pp2 + 1, __ATOMIC_RELAXED,
                                    __HIP_MEMORY_SCOPE_AGENT);
        }

        LGKM_BARRIER();  // own half of h_s[nxt] + Zx_s[nxt] ready

        // own-half K MFMA for step t+1 (slots 0-3) — covers exchange RTT
#pragma unroll
        for (int g = 0; g < 4; g++) accO[g] = (f32x4){0.f, 0.f, 0.f, 0.f};
#pragma unroll
        for (int kk = 0; kk < 4; kk++) {
            f16x8 afrag = *(const f16x8*)&h_s[nxt][c][kOwn + kk * 32];
#pragma unroll
            for (int g = 0; g < 4; g++) MFMA_A(accO[g], afrag, wha[g][kk]);
        }
    }

    if (!last) {
        int parity = (t0 + Tc) & 1;
        for (int idx = tau; idx < 16 * 128; idx += 512) {
            int r = idx >> 7, k = u0 + (idx & 127);
            Hstate[(b0 + r) * H_ + k] = h_s[parity][r][k];
        }
#pragma unroll
        for (int r = 0; r < 4; r++)
            Cstate[(b0 + q * 4 + r) * H_ + u] = cst[r];
    }
}

// ---------------------------------------------------------------------------
// K4: attention + head, 512 threads per batch row (verified round 7).
// vu for t < tstart is precomputed by fused vu producers; the last chunk's
// chapters run here (tau<256 guard, identical math). The T=512 weighted sum
// is split across two 256-thread groups and combined through LDS.
// ---------------------------------------------------------------------------
__global__ __launch_bounds__(512) void k4_attn(
    const f16* __restrict__ outs, const f16* __restrict__ WomT,
    const float* __restrict__ b_omega, const float* __restrict__ u_omega,
    const float* __restrict__ w, const float* __restrict__ bfin,
    const float* __restrict__ vuin, int tstart, float* __restrict__ out) {
    __shared__ __align__(16) f16 A_s[64][264];
    __shared__ __align__(16) f16 val_s[64][132];
    __shared__ float u_s[128];
    __shared__ float vu_s[512];
    __shared__ float red0[512], red1[512];

    int b = blockIdx.x, tau = threadIdx.x;  // 0..511
    int wave = tau >> 6, lane = tau & 63;
    int q = lane >> 4, c = lane & 15;

    if (tau < 128) u_s[tau] = u_omega[tau];
    float bom[8];
#pragma unroll
    for (int ni = 0; ni < 8; ni++) bom[ni] = b_omega[ni * 16 + c];

    // fill precomputed vu (tstart is a multiple of 64; 0 disables)
    for (int t = tau; t < tstart; t += 512) vu_s[t] = vuin[(size_t)b * T_ + t];

    for (int ch = tstart >> 6; ch < 8; ch++) {
        int t0c = ch * 64;
        __syncthreads();  // protects A_s/val_s reuse (+ covers u_s/vu fill)
        if (tau < 256) {  // stage 64 rows of outs
            int r = tau >> 2, seg = tau & 3;
            const f16x8* src =
                (const f16x8*)(outs + ((size_t)b * T_ + t0c + r) * H_ + seg * 64);
            f16x8* dst = (f16x8*)&A_s[r][seg * 64];
#pragma unroll
            for (int j = 0; j < 8; j++) dst[j] = src[j];
        }
        __syncthreads();
        if (tau < 256) {
            f32x4 acc[8];
#pragma unroll
            for (int ni = 0; ni < 8; ni++) acc[ni] = (f32x4){0.f, 0.f, 0.f, 0.f};
#pragma unroll
            for (int kc = 0; kc < 8; kc++) {
                f16x8 afrag = *(const f16x8*)&A_s[wave * 16 + c][kc * 32 + q * 8];
#pragma unroll
                for (int ni = 0; ni < 8; ni++) {
                    f16x8 bfrag = *(const f16x8*)(WomT +
                        (size_t)(ni * 16 + c) * 256 + kc * 32 + q * 8);
                    acc[ni] = __builtin_amdgcn_mfma_f32_16x16x32_f16(
                        afrag, bfrag, acc[ni], 0, 0, 0);
                }
            }
#pragma unroll
            for (int ni = 0; ni < 8; ni++) {
#pragma unroll
                for (int r = 0; r < 4; r++) {
                    val_s[wave * 16 + q * 4 + r][ni * 16 + c] =
                        (f16)tanh_f(acc[ni][r] + bom[ni]);
                }
            }
        }
        __syncthreads();
        if (tau < 64) {
            float s = 0.f;
#pragma unroll 8
            for (int a = 0; a < 128; a++) s += (float)val_s[tau][a] * u_s[a];
            vu_s[t0c + tau] = s;
        }
    }
    __syncthreads();

    // softmax over T=512, one element per thread
    red0[tau] = vu_s[tau];
    __syncthreads();
    for (int s = 256; s > 0; s >>= 1) {
        if (tau < s) red0[tau] = fmaxf(red0[tau], red0[tau + s]);
        __syncthreads();
    }
    float mx = red0[0];
    __syncthreads();
    float e = __expf(vu_s[tau] - mx);
    red0[tau] = e;
    __syncthreads();
    for (int s = 256; s > 0; s >>= 1) {
        if (tau < s) red0[tau] += red0[tau + s];
        __syncthreads();
    }
    float inv = 1.f / red0[0];
    __syncthreads();
    vu_s[tau] = e * inv;
    __syncthreads();

    // last[h] = sum_t alpha[t]*outs[b][t][h]; t split across two 256-thr groups
    int h = tau & 255, tg = tau >> 8;
    float lastv = 0.f;
    {
        const f16* orow = outs + ((size_t)b * T_ + tg * 256) * H_ + h;
        const float* al = &vu_s[tg * 256];
#pragma unroll 4
        for (int t = 0; t < 256; t++)
            lastv += al[t] * (float)orow[(size_t)t * H_];
    }
    red0[tau] = lastv;
    __syncthreads();
    float lsum = (tau < 256) ? red0[tau] + red0[tau + 256] : 0.f;
    __syncthreads();  // red0 reuse below

    // logits + 2-class softmax
    red0[tau] = (tau < 256) ? lsum * w[h * 2 + 0] : 0.f;
    red1[tau] = (tau < 256) ? lsum * w[h * 2 + 1] : 0.f;
    __syncthreads();
    for (int s = 256; s > 0; s >>= 1) {
        if (tau < s) {
            red0[tau] += red0[tau + s];
            red1[tau] += red1[tau + s];
        }
        __syncthreads();
    }
    if (tau == 0) {
        float l0 = red0[0] + bfin[0], l1 = red1[0] + bfin[1];
        float mm = fmaxf(l0, l1);
        float a0 = __expf(l0 - mm), a1 = __expf(l1 - mm);
        float den = a0 + a1;
        out[b * 2 + 0] = a0 / den;
        out[b * 2 + 1] = a1 / den;
    }
}

// ---------------------------------------------------------------------------
extern "C" void kernel_launch(void* const* d_in, const int* in_sizes, int n_in,
                              void* d_out, int out_size, void* d_ws,
                              size_t ws_size, hipStream_t stream) {
    const int*   x           = (const int*)d_in[0];
    const float* embed       = (const float*)d_in[1];
    const float* lstm_kernel = (const float*)d_in[2];
    const float* lstm_bias   = (const float*)d_in[3];
    const float* w_omega     = (const float*)d_in[4];
    const float* b_omega     = (const float*)d_in[5];
    const float* u_omega     = (const float*)d_in[6];
    const float* w           = (const float*)d_in[7];
    const float* bfin        = (const float*)d_in[8];
    float*       out         = (float*)d_out;

    char* ws = (char*)d_ws;
    f16*   WxT    = (f16*)(ws + 0);              //  524288 B
    f16*   WhT    = (f16*)(ws + 524288);         //  524288 B
    f16*   WomT   = (f16*)(ws + 1048576);        //   65536 B
    int*   seqlen = (int*)(ws + 1114112);        //    1024 B
    f16*   Hstate = (f16*)(ws + 1115136);        //  131072 B
    float* Cstate = (float*)(ws + 1246208);      //  262144 B
    u32*   Hex    = (u32*)(ws + 1508352);        //  524288 B (32 wg x 16KB)
    float* vu     = (float*)(ws + 2032640);      //  524288 B (B x T f32)
    f16*   outs   = (f16*)(ws + 2556928);        // 67108864 B

    // Zx double buffer for producer-fusion: need fixed + 2 chunks <= ws.
    const size_t fixed = 2556928ull + 67108864ull;
    int nch = 1;
    while (nch < 16 && fixed + 2ull * (268435456ull / (size_t)nch) > ws_size)
        nch <<= 1;
    int Tc = T_ / nch;
    size_t chunkB = 268435456ull / (size_t)nch;
    f16* ZxA = (f16*)(ws + fixed);
    f16* ZxB = (f16*)(ws + fixed + chunkB);  // unused when nch == 1

    // vu fusion requires chunk length a multiple of the 64-step chapter size
    int vuEnable = (Tc % 64 == 0) && (nch >= 2);
    int tstart   = vuEnable ? (nch - 1) * Tc : 0;

    // k0 (weights) + seqlen fused in one launch
    k0_convert<<<N4H + A_ + B_, 256, 0, stream>>>(lstm_kernel, w_omega, WxT,
                                                  WhT, WomT, x, seqlen);
    // chunk 0's Zx standalone (512-thr, 128 rows/block)
    k2b_zx<<<(B_ * Tc) / 128, 512, 0, stream>>>(x, embed, WxT, lstm_bias, ZxA,
                                                0, Tc);
    for (int chk = 0; chk < nch; chk++) {
        int  t0  = chk * Tc;
        f16* zc  = (chk & 1) ? ZxB : ZxA;
        f16* zn  = (chk & 1) ? ZxA : ZxB;
        int  npz = (chk + 1 < nch) ? (B_ * Tc) / 128 : 0;  // Zx producer blocks
        int  nv  = (vuEnable && chk >= 1) ? B_ : 0;        // vu producer blocks
        int  t0n = (chk + 1) * Tc;
        int  t0v = (chk - 1) * Tc;
        k3_lstm<<<32 + npz + nv, 512, 0, stream>>>(
            zc, WhT, seqlen, outs, Hstate, Cstate, Hex, t0, Tc,
            chk == 0 ? 1 : 0, chk == nch - 1 ? 1 : 0,
            x, embed, WxT, lstm_bias, zn, t0n, npz,
            WomT, b_omega, u_omega, vu, t0v);
    }
    k4_attn<<<256, 512, 0, stream>>>(outs, WomT, b_omega, u_omega, w, bfin,
                                     vu, tstart, out);
}